// Round 1
// baseline (460.232 us; speedup 1.0000x reference)
//
#include <hip/hip_runtime.h>

// ScaledDotProductAttention: B=16, S=2048, D=64, T=8
constexpr int NB = 16;
constexpr int NS = 2048;
constexpr int ND = 64;
constexpr int MTILE = 16;              // query rows per block (16 -> 2 blocks/CU)
constexpr int NW32 = NS / 32;          // packed mask words per row

typedef __attribute__((ext_vector_type(8))) short bh8;            // 8 x bf16 (4 VGPRs)
typedef __attribute__((ext_vector_type(4))) float f32x4;          // MFMA accumulator
typedef __attribute__((ext_vector_type(4))) unsigned short us4;   // 4 x bf16 store

constexpr int EB_STRIDE = 2048 + 8;    // bf16/row: 4112B = 257*16 (16B align kept, pow2 bank stride broken)

__device__ __forceinline__ unsigned short f2bf(float x) {
  unsigned u = __float_as_uint(x);
  u += 0x7fffu + ((u >> 16) & 1u);     // round-to-nearest-even
  return (unsigned short)(u >> 16);
}
__device__ __forceinline__ float bf2f(unsigned u16) {
  return __uint_as_float(u16 << 16);
}

// ---- Kernel 0a: Vt[b][d][k] = bf16(V[b][k][d])  AND  Kbf[b][k][d] = bf16(K[b][k][d]).
// Vt makes the PV B-fragment one contiguous 16B load; Kbf makes the QK^T B-fragment one
// contiguous 16B load and removes the per-block f32->bf16 convert (was done 128x redundantly).
__global__ __launch_bounds__(256)
void prep_kv_kernel(const float* __restrict__ v, const float* __restrict__ k,
                    unsigned short* __restrict__ vt, unsigned short* __restrict__ kbf) {
  __shared__ float tile[64][65];
  const int b   = blockIdx.y;
  const int kc  = blockIdx.x;          // 64-key chunk
  const int tid = threadIdx.x;
  const int r0  = tid >> 4;            // 0..15
  const int c0  = (tid & 15) * 4;      // 0..60
  #pragma unroll
  for (int p = 0; p < 4; ++p) {
    const int krow = p * 16 + r0;
    const long base = ((long)(b * NS) + kc * 64 + krow) * ND + c0;
    float4 vv = *(const float4*)(v + base);
    tile[c0 + 0][krow] = vv.x;
    tile[c0 + 1][krow] = vv.y;
    tile[c0 + 2][krow] = vv.z;
    tile[c0 + 3][krow] = vv.w;
    float4 kk4 = *(const float4*)(k + base);
    us4 ko;
    ko.x = f2bf(kk4.x); ko.y = f2bf(kk4.y); ko.z = f2bf(kk4.z); ko.w = f2bf(kk4.w);
    *(us4*)(kbf + base) = ko;          // same [b][s][d] layout, bf16
  }
  __syncthreads();
  #pragma unroll
  for (int p = 0; p < 4; ++p) {
    const int d = p * 16 + r0;
    us4 o;
    o.x = f2bf(tile[d][c0 + 0]);
    o.y = f2bf(tile[d][c0 + 1]);
    o.z = f2bf(tile[d][c0 + 2]);
    o.w = f2bf(tile[d][c0 + 3]);
    *(us4*)(vt + ((long)(b * 64 + d)) * NS + kc * 64 + c0) = o;
  }
}

// ---- Kernel 0b: bit-pack mask [1][S][S] int32 -> [S][S/32] uint32 (512 KB, L2-resident).
// Phase 1 then needs ONE quad-uniform 4B word per 32 keys per row instead of 32 scattered
// 4B loads from a 16 MiB (L3-latency) stream.
__global__ __launch_bounds__(256)
void maskpack_kernel(const int* __restrict__ mask, unsigned* __restrict__ mbits) {
  const int row = blockIdx.y;
  const int col = blockIdx.x * 256 + threadIdx.x;
  const unsigned long long bal = __ballot(mask[(long)row * NS + col] != 0);
  const int lane = threadIdx.x & 63;
  if (lane == 0)       mbits[row * NW32 + (col >> 5)] = (unsigned)bal;
  else if (lane == 32) mbits[row * NW32 + (col >> 5)] = (unsigned)(bal >> 32);
}

// ---- Kernel 1: fused scores+softmax+attn-write+PV. 512 threads, 70.5KB LDS -> 2 blocks/CU
// (two independent barrier domains per CU was the R3 lesson: occupancy inside ONE barrier
// domain doesn't hide barrier stalls).
__global__ __launch_bounds__(512, 1)
void sdpa_fused_kernel(const float* __restrict__ q, const unsigned short* __restrict__ kbf,
                       const unsigned* __restrict__ mbits, const unsigned short* __restrict__ vt,
                       float* __restrict__ outO, float* __restrict__ outA)
{
  extern __shared__ char smem[];
  unsigned short* ebuf = (unsigned short*)smem;       // [16][EB_STRIDE] bf16 e=exp(s)
  float* rowsumP = (float*)(ebuf + MTILE * EB_STRIDE);// [16][8] partial row sums
  float* invl    = rowsumP + 16 * 8;                  // [16]
  float* osum    = invl + 16;                         // [4][64][4] phase-3 K-half reduce

  const int tid  = threadIdx.x;
  const int wave = tid >> 6;
  const int lane = tid & 63;
  const int n16  = lane & 15;
  const int quad = lane >> 4;
  const int b     = blockIdx.y;
  const int mbase = blockIdx.x * MTILE;

  // ---- Phase 1: 8 waves x 256-key chunks. All waves share the same 16 query rows.
  const int col0 = wave * 256;
  const int r0q  = quad * 4;           // this quad's first C/D row

  // Q fragment (A-operand: lane holds A[m=lane&15][k=quad*8+j]), pre-scaled by 1/8
  bh8 aq[2];
  {
    const float* qp = q + ((long)(b * NS + mbase + n16)) * ND + quad * 8;
    #pragma unroll
    for (int kk = 0; kk < 2; ++kk) {
      float4 x0 = *(const float4*)(qp + kk * 32);
      float4 x1 = *(const float4*)(qp + kk * 32 + 4);
      bh8 f;
      f[0] = f2bf(x0.x * 0.125f); f[1] = f2bf(x0.y * 0.125f);
      f[2] = f2bf(x0.z * 0.125f); f[3] = f2bf(x0.w * 0.125f);
      f[4] = f2bf(x1.x * 0.125f); f[5] = f2bf(x1.y * 0.125f);
      f[6] = f2bf(x1.z * 0.125f); f[7] = f2bf(x1.w * 0.125f);
      aq[kk] = f;
    }
  }

  // S = (Q/8)K^T via MFMA; e = mask ? exp(s) : 0 -> ebuf; accumulate row sums.
  const unsigned short* kbp = kbf + (long)(b * NS) * ND;
  float rsum[4] = {0.f, 0.f, 0.f, 0.f};
  #pragma unroll 2
  for (int nt2 = 0; nt2 < 8; ++nt2) {
    // One packed-mask word covers 32 keys for each of this quad's 4 rows (quad-uniform load).
    unsigned mrow[4];
    #pragma unroll
    for (int r = 0; r < 4; ++r)
      mrow[r] = mbits[(long)(mbase + r0q + r) * NW32 + (col0 >> 5) + nt2];
    #pragma unroll
    for (int half = 0; half < 2; ++half) {
      const int key = col0 + nt2 * 32 + half * 16 + n16;
      const unsigned short* kp = kbp + (long)key * ND + quad * 8;
      bh8 f0 = *(const bh8*)(kp);        // B-operand: lane holds B[k=quad*8+j][n=n16]=K[key][kdim]
      bh8 f1 = *(const bh8*)(kp + 32);
      f32x4 acc = {0.f, 0.f, 0.f, 0.f};
      acc = __builtin_amdgcn_mfma_f32_16x16x32_bf16(aq[0], f0, acc, 0, 0, 0);
      acc = __builtin_amdgcn_mfma_f32_16x16x32_bf16(aq[1], f1, acc, 0, 0, 0);
      // C/D layout: col = lane&15 (== key), row = quad*4 + r
      #pragma unroll
      for (int r = 0; r < 4; ++r) {
        const unsigned bit = (mrow[r] >> (half * 16 + n16)) & 1u;
        const float e = bit ? __expf(acc[r]) : 0.f;
        rsum[r] += e;
        ebuf[(r0q + r) * EB_STRIDE + key] = f2bf(e);
      }
    }
  }

  #pragma unroll
  for (int r = 0; r < 4; ++r) {
    float s = rsum[r];
    s += __shfl_xor(s, 1);
    s += __shfl_xor(s, 2);
    s += __shfl_xor(s, 4);
    s += __shfl_xor(s, 8);
    if (n16 == 0) rowsumP[(r0q + r) * 8 + wave] = s;
  }
  __syncthreads();
  if (tid < 16) {
    float l = 0.f;
    #pragma unroll
    for (int c = 0; c < 8; ++c) l += rowsumP[tid * 8 + c];
    invl[tid] = 1.f / l;
  }
  __syncthreads();

  // ---- Phase 2: attn = e * invl -> global (one row / iteration, float4-coalesced)
  {
    float* aout = outA + ((long)(b * NS + mbase)) * NS;
    const int c4 = tid * 4;
    #pragma unroll 2
    for (int row = 0; row < MTILE; ++row) {
      const float il = invl[row];
      uint2 raw = *(const uint2*)(ebuf + row * EB_STRIDE + c4);
      float4 o;
      o.x = bf2f(raw.x & 0xffffu) * il;
      o.y = bf2f(raw.x >> 16)     * il;
      o.z = bf2f(raw.y & 0xffffu) * il;
      o.w = bf2f(raw.y >> 16)     * il;
      *(float4*)(aout + (long)row * NS + c4) = o;
    }
  }

  // ---- Phase 3: O = P V via MFMA. B-fragment = 16B contiguous load from Vt (L2-hot).
  // ZERO barriers in the loop. 8 waves = 4 d-tiles x 2 K-halves.
  const int dtile = wave & 3;
  const int khalf = wave >> 2;
  const int kbase = khalf * 1024;
  const unsigned short* vrow = vt + ((long)(b * 64 + dtile * 16 + n16)) * NS + kbase + quad * 8;
  f32x4 oacc = {0.f, 0.f, 0.f, 0.f};
  #pragma unroll 4
  for (int kc = 0; kc < 32; ++kc) {
    const int k0 = kbase + kc * 32;
    bh8 af = *(const bh8*)(ebuf + n16 * EB_STRIDE + k0 + quad * 8);
    bh8 bf = *(const bh8*)(vrow + kc * 32);
    oacc = __builtin_amdgcn_mfma_f32_16x16x32_bf16(af, bf, oacc, 0, 0, 0);
  }
  // K-half reduce via LDS, then scale by invl and store O.
  if (khalf == 1) *(f32x4*)(osum + (dtile * 64 + lane) * 4) = oacc;
  __syncthreads();
  if (khalf == 0) {
    f32x4 other = *(const f32x4*)(osum + (dtile * 64 + lane) * 4);
    #pragma unroll
    for (int r = 0; r < 4; ++r) {
      const int lrow = quad * 4 + r;   // C/D: col = n16 (d), row = quad*4+r (query row)
      outO[((long)(b * NS + mbase + lrow)) * ND + dtile * 16 + n16] =
          (oacc[r] + other[r]) * invl[lrow];
    }
  }
}

extern "C" void kernel_launch(void* const* d_in, const int* in_sizes, int n_in,
                              void* d_out, int out_size, void* d_ws, size_t ws_size,
                              hipStream_t stream) {
  const float* q    = (const float*)d_in[0];
  const float* k    = (const float*)d_in[1];
  const float* v    = (const float*)d_in[2];
  const int*   mask = (const int*)d_in[3];
  float* outO = (float*)d_out;                      // [16,2048,64]
  float* outA = outO + (long)NB * NS * ND;          // [16,2048,2048]

  // workspace: vt [16][64][2048] bf16 | kbf [16][2048][64] bf16 | mbits [2048][64] u32
  unsigned short* vt    = (unsigned short*)d_ws;
  unsigned short* kbf   = vt + (long)NB * ND * NS;
  unsigned*       mbits = (unsigned*)(kbf + (long)NB * NS * ND);

  prep_kv_kernel<<<dim3(NS / 64, NB), 256, 0, stream>>>(v, k, vt, kbf);
  maskpack_kernel<<<dim3(NS / 256, NS), 256, 0, stream>>>(mask, mbits);

  const size_t lds = (size_t)(MTILE * EB_STRIDE) * sizeof(short)
                   + (size_t)(16 * 8 + 16 + 4 * 64 * 4) * sizeof(float);
  hipFuncSetAttribute((const void*)sdpa_fused_kernel,
                      hipFuncAttributeMaxDynamicSharedMemorySize, (int)lds);
  sdpa_fused_kernel<<<dim3(NS / MTILE, NB), 512, lds, stream>>>(q, kbf, mbits, vt, outO, outA);
}

// Round 2
// 400.303 us; speedup vs baseline: 1.1497x; 1.1497x over previous
//
#include <hip/hip_runtime.h>

// ScaledDotProductAttention: B=16, S=2048, D=64, T=8
constexpr int NB = 16;
constexpr int NS = 2048;
constexpr int ND = 64;
constexpr int MTILE = 16;              // query rows per block (16 -> 2 blocks/CU)
constexpr int NW32 = NS / 32;          // packed mask words per row

typedef __attribute__((ext_vector_type(8))) short bh8;            // 8 x bf16 (4 VGPRs)
typedef __attribute__((ext_vector_type(4))) float f32x4;          // MFMA accumulator
typedef __attribute__((ext_vector_type(4))) unsigned short us4;   // 4 x bf16 store

constexpr int EB_STRIDE = 2048 + 8;    // bf16/row: 4112B = 257*16 (16B align kept, pow2 bank stride broken)

__device__ __forceinline__ unsigned short f2bf(float x) {
  unsigned u = __float_as_uint(x);
  u += 0x7fffu + ((u >> 16) & 1u);     // round-to-nearest-even
  return (unsigned short)(u >> 16);
}
__device__ __forceinline__ float bf2f(unsigned u16) {
  return __uint_as_float(u16 << 16);
}

// ---- Kernel 0a: Vt[b][d][k] = bf16(V[b][k][d])  AND  Kbf[b][k][d] = bf16(K[b][k][d]).
__global__ __launch_bounds__(256)
void prep_kv_kernel(const float* __restrict__ v, const float* __restrict__ k,
                    unsigned short* __restrict__ vt, unsigned short* __restrict__ kbf) {
  __shared__ float tile[64][65];
  const int b   = blockIdx.y;
  const int kc  = blockIdx.x;          // 64-key chunk
  const int tid = threadIdx.x;
  const int r0  = tid >> 4;            // 0..15
  const int c0  = (tid & 15) * 4;      // 0..60
  #pragma unroll
  for (int p = 0; p < 4; ++p) {
    const int krow = p * 16 + r0;
    const long base = ((long)(b * NS) + kc * 64 + krow) * ND + c0;
    float4 vv = *(const float4*)(v + base);
    tile[c0 + 0][krow] = vv.x;
    tile[c0 + 1][krow] = vv.y;
    tile[c0 + 2][krow] = vv.z;
    tile[c0 + 3][krow] = vv.w;
    float4 kk4 = *(const float4*)(k + base);
    us4 ko;
    ko.x = f2bf(kk4.x); ko.y = f2bf(kk4.y); ko.z = f2bf(kk4.z); ko.w = f2bf(kk4.w);
    *(us4*)(kbf + base) = ko;          // same [b][s][d] layout, bf16
  }
  __syncthreads();
  #pragma unroll
  for (int p = 0; p < 4; ++p) {
    const int d = p * 16 + r0;
    us4 o;
    o.x = f2bf(tile[d][c0 + 0]);
    o.y = f2bf(tile[d][c0 + 1]);
    o.z = f2bf(tile[d][c0 + 2]);
    o.w = f2bf(tile[d][c0 + 3]);
    *(us4*)(vt + ((long)(b * 64 + d)) * NS + kc * 64 + c0) = o;
  }
}

// ---- Kernel 0b: bit-pack mask [1][S][S] int32 -> [S][S/32] uint32 (512 KB, L2-resident).
__global__ __launch_bounds__(256)
void maskpack_kernel(const int* __restrict__ mask, unsigned* __restrict__ mbits) {
  const int row = blockIdx.y;
  const int col = blockIdx.x * 256 + threadIdx.x;
  const unsigned long long bal = __ballot(mask[(long)row * NS + col] != 0);
  const int lane = threadIdx.x & 63;
  if (lane == 0)       mbits[row * NW32 + (col >> 5)] = (unsigned)bal;
  else if (lane == 32) mbits[row * NW32 + (col >> 5)] = (unsigned)(bal >> 32);
}

// ---- Kernel 1: fused scores+softmax+attn-write+PV.
// R2 changes: (a) XCD-chunked block swizzle so each XCD's L2 holds only 2 batches' K/V;
// (b) nontemporal attn/O stores so the 256MiB write stream doesn't evict K/V from L2;
// (c) explicit double-buffered K/mask prefetch in phase 1 (compiler kept nothing in
//     flight at VGPR=40); (d) phase 2 row-stores interleaved into phase 3's MFMA loop
//     so the write stream is spread over the timeline instead of per-block bursts.
__global__ __launch_bounds__(512, 1)
void sdpa_fused_kernel(const float* __restrict__ q, const unsigned short* __restrict__ kbf,
                       const unsigned* __restrict__ mbits, const unsigned short* __restrict__ vt,
                       float* __restrict__ outO, float* __restrict__ outA)
{
  extern __shared__ char smem[];
  unsigned short* ebuf = (unsigned short*)smem;       // [16][EB_STRIDE] bf16 e=exp(s)
  float* rowsumP = (float*)(ebuf + MTILE * EB_STRIDE);// [16][8] partial row sums
  float* invl    = rowsumP + 16 * 8;                  // [16]
  float* osum    = invl + 16;                         // [4][64][4] phase-3 K-half reduce

  const int tid  = threadIdx.x;
  const int wave = tid >> 6;
  const int lane = tid & 63;
  const int n16  = lane & 15;
  const int quad = lane >> 4;

  // XCD-chunked swizzle: dispatch round-robins XCDs on linear id, so id%8==j all land
  // on XCD j; give XCD j the contiguous work chunk [j*256, j*256+256) = 2 batches.
  const int bid   = blockIdx.y * gridDim.x + blockIdx.x;   // 0..2047
  const int swz   = (bid & 7) * 256 + (bid >> 3);
  const int b     = swz >> 7;                              // /128 -> batch
  const int mbase = (swz & 127) * MTILE;

  // ---- Phase 1: 8 waves x 256-key chunks. All waves share the same 16 query rows.
  const int col0 = wave * 256;
  const int r0q  = quad * 4;           // this quad's first C/D row

  // Q fragment (A-operand: lane holds A[m=lane&15][k=quad*8+j]), pre-scaled by 1/8
  bh8 aq[2];
  {
    const float* qp = q + ((long)(b * NS + mbase + n16)) * ND + quad * 8;
    #pragma unroll
    for (int kk = 0; kk < 2; ++kk) {
      float4 x0 = *(const float4*)(qp + kk * 32);
      float4 x1 = *(const float4*)(qp + kk * 32 + 4);
      bh8 f;
      f[0] = f2bf(x0.x * 0.125f); f[1] = f2bf(x0.y * 0.125f);
      f[2] = f2bf(x0.z * 0.125f); f[3] = f2bf(x0.w * 0.125f);
      f[4] = f2bf(x1.x * 0.125f); f[5] = f2bf(x1.y * 0.125f);
      f[6] = f2bf(x1.z * 0.125f); f[7] = f2bf(x1.w * 0.125f);
      aq[kk] = f;
    }
  }

  // S = (Q/8)K^T via MFMA; e = mask ? exp(s) : 0 -> ebuf; accumulate row sums.
  // 8 groups of 32 keys, software-pipelined with explicit A/B register buffers
  // (all indices compile-time -> stays in VGPRs).
  const unsigned short* kbp = kbf + (long)(b * NS) * ND + quad * 8;
  float rsum[4] = {0.f, 0.f, 0.f, 0.f};

#define LOADG(kf, mw, g) do {                                                   \
    const int kk0 = col0 + (g) * 32;                                            \
    const unsigned short* kp = kbp + (long)(kk0 + n16) * ND;                    \
    kf[0] = *(const bh8*)(kp);                                                  \
    kf[1] = *(const bh8*)(kp + 32);                                             \
    kf[2] = *(const bh8*)(kp + 16 * ND);                                        \
    kf[3] = *(const bh8*)(kp + 16 * ND + 32);                                   \
    _Pragma("unroll")                                                           \
    for (int r = 0; r < 4; ++r)                                                 \
      mw[r] = mbits[(long)(mbase + r0q + r) * NW32 + (kk0 >> 5)];               \
  } while (0)

#define COMPUTEG(kf, mw, g) do {                                                \
    _Pragma("unroll")                                                           \
    for (int h = 0; h < 2; ++h) {                                               \
      f32x4 acc = {0.f, 0.f, 0.f, 0.f};                                         \
      acc = __builtin_amdgcn_mfma_f32_16x16x32_bf16(aq[0], kf[2*h],   acc,0,0,0);\
      acc = __builtin_amdgcn_mfma_f32_16x16x32_bf16(aq[1], kf[2*h+1], acc,0,0,0);\
      const int key = col0 + (g) * 32 + h * 16 + n16;                           \
      _Pragma("unroll")                                                         \
      for (int r = 0; r < 4; ++r) {                                             \
        const unsigned bit = (mw[r] >> (h * 16 + n16)) & 1u;                    \
        const float e = bit ? __expf(acc[r]) : 0.f;                             \
        rsum[r] += e;                                                           \
        ebuf[(r0q + r) * EB_STRIDE + key] = f2bf(e);                            \
      }                                                                         \
    }                                                                           \
  } while (0)

  {
    bh8 kfA[4], kfB[4];
    unsigned mwA[4], mwB[4];
    LOADG(kfA, mwA, 0); LOADG(kfB, mwB, 1);
    COMPUTEG(kfA, mwA, 0); LOADG(kfA, mwA, 2);
    COMPUTEG(kfB, mwB, 1); LOADG(kfB, mwB, 3);
    COMPUTEG(kfA, mwA, 2); LOADG(kfA, mwA, 4);
    COMPUTEG(kfB, mwB, 3); LOADG(kfB, mwB, 5);
    COMPUTEG(kfA, mwA, 4); LOADG(kfA, mwA, 6);
    COMPUTEG(kfB, mwB, 5); LOADG(kfB, mwB, 7);
    COMPUTEG(kfA, mwA, 6);
    COMPUTEG(kfB, mwB, 7);
  }
#undef LOADG
#undef COMPUTEG

  #pragma unroll
  for (int r = 0; r < 4; ++r) {
    float s = rsum[r];
    s += __shfl_xor(s, 1);
    s += __shfl_xor(s, 2);
    s += __shfl_xor(s, 4);
    s += __shfl_xor(s, 8);
    if (n16 == 0) rowsumP[(r0q + r) * 8 + wave] = s;
  }
  __syncthreads();
  if (tid < 16) {
    float l = 0.f;
    #pragma unroll
    for (int c = 0; c < 8; ++c) l += rowsumP[tid * 8 + c];
    invl[tid] = 1.f / l;
  }
  __syncthreads();

  // ---- Phase 2+3 merged: O = P V via MFMA, with one attn row-store interleaved per
  // two MFMA iterations (spreads the 256MiB write stream over the whole window).
  // 8 waves = 4 d-tiles x 2 K-halves. Nontemporal stores keep the stream out of L2.
  const int dtile = wave & 3;
  const int khalf = wave >> 2;
  const int kb    = khalf * 1024;
  const unsigned short* vrow = vt + ((long)(b * 64 + dtile * 16 + n16)) * NS + kb + quad * 8;
  float* aout = outA + ((long)(b * NS + mbase)) * NS;
  const int c4 = tid * 4;
  f32x4 oacc = {0.f, 0.f, 0.f, 0.f};
  #pragma unroll 8
  for (int kc = 0; kc < 32; ++kc) {
    const int k0 = kb + kc * 32;
    bh8 af  = *(const bh8*)(ebuf + n16 * EB_STRIDE + k0 + quad * 8);
    bh8 bfv = *(const bh8*)(vrow + kc * 32);
    oacc = __builtin_amdgcn_mfma_f32_16x16x32_bf16(af, bfv, oacc, 0, 0, 0);
    if (kc & 1) {
      const int row = kc >> 1;                    // rows 0..15 over odd kc
      const float il = invl[row];
      uint2 raw = *(const uint2*)(ebuf + row * EB_STRIDE + c4);
      f32x4 o;
      o[0] = bf2f(raw.x & 0xffffu) * il;
      o[1] = bf2f(raw.x >> 16)     * il;
      o[2] = bf2f(raw.y & 0xffffu) * il;
      o[3] = bf2f(raw.y >> 16)     * il;
      __builtin_nontemporal_store(o, (f32x4*)(aout + (long)row * NS + c4));
    }
  }
  // K-half reduce via LDS, then scale by invl and store O.
  if (khalf == 1) *(f32x4*)(osum + (dtile * 64 + lane) * 4) = oacc;
  __syncthreads();
  if (khalf == 0) {
    f32x4 other = *(const f32x4*)(osum + (dtile * 64 + lane) * 4);
    #pragma unroll
    for (int r = 0; r < 4; ++r) {
      const int lrow = quad * 4 + r;   // C/D: col = n16 (d), row = quad*4+r (query row)
      __builtin_nontemporal_store(
          (oacc[r] + other[r]) * invl[lrow],
          outO + ((long)(b * NS + mbase + lrow)) * ND + dtile * 16 + n16);
    }
  }
}

extern "C" void kernel_launch(void* const* d_in, const int* in_sizes, int n_in,
                              void* d_out, int out_size, void* d_ws, size_t ws_size,
                              hipStream_t stream) {
  const float* q    = (const float*)d_in[0];
  const float* k    = (const float*)d_in[1];
  const float* v    = (const float*)d_in[2];
  const int*   mask = (const int*)d_in[3];
  float* outO = (float*)d_out;                      // [16,2048,64]
  float* outA = outO + (long)NB * NS * ND;          // [16,2048,2048]

  // workspace: vt [16][64][2048] bf16 | kbf [16][2048][64] bf16 | mbits [2048][64] u32
  unsigned short* vt    = (unsigned short*)d_ws;
  unsigned short* kbf   = vt + (long)NB * ND * NS;
  unsigned*       mbits = (unsigned*)(kbf + (long)NB * NS * ND);

  prep_kv_kernel<<<dim3(NS / 64, NB), 256, 0, stream>>>(v, k, vt, kbf);
  maskpack_kernel<<<dim3(NS / 256, NS), 256, 0, stream>>>(mask, mbits);

  const size_t lds = (size_t)(MTILE * EB_STRIDE) * sizeof(short)
                   + (size_t)(16 * 8 + 16 + 4 * 64 * 4) * sizeof(float);
  hipFuncSetAttribute((const void*)sdpa_fused_kernel,
                      hipFuncAttributeMaxDynamicSharedMemorySize, (int)lds);
  sdpa_fused_kernel<<<dim3(NS / MTILE, NB), 512, lds, stream>>>(q, kbf, mbits, vt, outO, outA);
}

// Round 4
// 399.177 us; speedup vs baseline: 1.1530x; 1.0028x over previous
//
#include <hip/hip_runtime.h>

// ScaledDotProductAttention: B=16, S=2048, D=64, T=8
constexpr int NB = 16;
constexpr int NS = 2048;
constexpr int ND = 64;
constexpr int MTILE = 16;              // query rows per block (16 -> 2 blocks/CU)
constexpr int NW32 = NS / 32;          // packed mask words per row

typedef __attribute__((ext_vector_type(8))) short bh8;            // 8 x bf16 (4 VGPRs)
typedef __attribute__((ext_vector_type(4))) float f32x4;          // MFMA accumulator
typedef __attribute__((ext_vector_type(4))) unsigned short us4;   // 4 x bf16 store

constexpr int EB_STRIDE = 2048 + 8;    // bf16/row: 4112B = 257*16 (16B align kept, pow2 bank stride broken)

__device__ __forceinline__ unsigned short f2bf(float x) {
  unsigned u = __float_as_uint(x);
  u += 0x7fffu + ((u >> 16) & 1u);     // round-to-nearest-even
  return (unsigned short)(u >> 16);
}
__device__ __forceinline__ float bf2f(unsigned u16) {
  return __uint_as_float(u16 << 16);
}

// ---- Kernel 0a: Vt[b][d][k] = bf16(V[b][k][d])  AND  Kbf[b][k][d] = bf16(K[b][k][d]).
__global__ __launch_bounds__(256)
void prep_kv_kernel(const float* __restrict__ v, const float* __restrict__ k,
                    unsigned short* __restrict__ vt, unsigned short* __restrict__ kbf) {
  __shared__ float tile[64][65];
  const int b   = blockIdx.y;
  const int kc  = blockIdx.x;          // 64-key chunk
  const int tid = threadIdx.x;
  const int r0  = tid >> 4;            // 0..15
  const int c0  = (tid & 15) * 4;      // 0..60
  #pragma unroll
  for (int p = 0; p < 4; ++p) {
    const int krow = p * 16 + r0;
    const long base = ((long)(b * NS) + kc * 64 + krow) * ND + c0;
    float4 vv = *(const float4*)(v + base);
    tile[c0 + 0][krow] = vv.x;
    tile[c0 + 1][krow] = vv.y;
    tile[c0 + 2][krow] = vv.z;
    tile[c0 + 3][krow] = vv.w;
    float4 kk4 = *(const float4*)(k + base);
    us4 ko;
    ko.x = f2bf(kk4.x); ko.y = f2bf(kk4.y); ko.z = f2bf(kk4.z); ko.w = f2bf(kk4.w);
    *(us4*)(kbf + base) = ko;          // same [b][s][d] layout, bf16
  }
  __syncthreads();
  #pragma unroll
  for (int p = 0; p < 4; ++p) {
    const int d = p * 16 + r0;
    us4 o;
    o.x = f2bf(tile[d][c0 + 0]);
    o.y = f2bf(tile[d][c0 + 1]);
    o.z = f2bf(tile[d][c0 + 2]);
    o.w = f2bf(tile[d][c0 + 3]);
    *(us4*)(vt + ((long)(b * 64 + d)) * NS + kc * 64 + c0) = o;
  }
}

// ---- Kernel 0b: bit-pack mask [1][S][S] int32 -> [S][S/32] uint32 (512 KB, L2-resident).
__global__ __launch_bounds__(256)
void maskpack_kernel(const int* __restrict__ mask, unsigned* __restrict__ mbits) {
  const int row = blockIdx.y;
  const int col = blockIdx.x * 256 + threadIdx.x;
  const unsigned long long bal = __ballot(mask[(long)row * NS + col] != 0);
  const int lane = threadIdx.x & 63;
  if (lane == 0)       mbits[row * NW32 + (col >> 5)] = (unsigned)bal;
  else if (lane == 32) mbits[row * NW32 + (col >> 5)] = (unsigned)(bal >> 32);
}

// ---- Kernel 1: fused scores+softmax+attn-write+PV.
// R4 = R2-verified phase 1 (__expf, 0.125 scale, launch_bounds(512,1)) + R3's structural
// wins only: depth-3 register pipeline in phase 2/3, V prefetch issued before the softmax
// barriers, invl in registers for the (compile-time-indexed) attn path. The R3 failure is
// attributed to the inline-asm v_exp_f32 (trans-op hazard invisible to the compiler's
// hazard recognizer -> stale-register reads); reverted to __expf.
__global__ __launch_bounds__(512, 1)
void sdpa_fused_kernel(const float* __restrict__ q, const unsigned short* __restrict__ kbf,
                       const unsigned* __restrict__ mbits, const unsigned short* __restrict__ vt,
                       float* __restrict__ outO, float* __restrict__ outA)
{
  extern __shared__ char smem[];
  unsigned short* ebuf = (unsigned short*)smem;       // [16][EB_STRIDE] bf16 e=exp(s)
  float* rowsumP = (float*)(ebuf + MTILE * EB_STRIDE);// [16][8] partial row sums
  float* invl    = rowsumP + 16 * 8;                  // [16]
  float* osum    = invl + 16;                         // [4][64][4] phase-3 K-half reduce

  const int tid  = threadIdx.x;
  const int wave = tid >> 6;
  const int lane = tid & 63;
  const int n16  = lane & 15;
  const int quad = lane >> 4;

  // XCD-chunked swizzle: dispatch round-robins XCDs on linear id, so id%8==j all land
  // on XCD j; give XCD j the contiguous work chunk [j*256, j*256+256) = 2 batches.
  const int bid   = blockIdx.y * gridDim.x + blockIdx.x;   // 0..2047
  const int swz   = (bid & 7) * 256 + (bid >> 3);
  const int b     = swz >> 7;                              // /128 -> batch
  const int mbase = (swz & 127) * MTILE;

  // ---- Phase 1: 8 waves x 256-key chunks. All waves share the same 16 query rows.
  const int col0 = wave * 256;
  const int r0q  = quad * 4;           // this quad's first C/D row

  // Q fragment (A-operand: lane holds A[m=lane&15][k=quad*8+j]), pre-scaled by 1/8
  bh8 aq[2];
  {
    const float* qp = q + ((long)(b * NS + mbase + n16)) * ND + quad * 8;
    #pragma unroll
    for (int kk = 0; kk < 2; ++kk) {
      float4 x0 = *(const float4*)(qp + kk * 32);
      float4 x1 = *(const float4*)(qp + kk * 32 + 4);
      bh8 f;
      f[0] = f2bf(x0.x * 0.125f); f[1] = f2bf(x0.y * 0.125f);
      f[2] = f2bf(x0.z * 0.125f); f[3] = f2bf(x0.w * 0.125f);
      f[4] = f2bf(x1.x * 0.125f); f[5] = f2bf(x1.y * 0.125f);
      f[6] = f2bf(x1.z * 0.125f); f[7] = f2bf(x1.w * 0.125f);
      aq[kk] = f;
    }
  }

  // S = (Q/8)K^T via MFMA; e = mask ? exp(s) : 0 -> ebuf; accumulate row sums.
  const unsigned short* kbp = kbf + (long)(b * NS) * ND + quad * 8;
  float rsum[4] = {0.f, 0.f, 0.f, 0.f};

#define LOADG(kf, mw, g) do {                                                   \
    const int kk0 = col0 + (g) * 32;                                            \
    const unsigned short* kp = kbp + (long)(kk0 + n16) * ND;                    \
    kf[0] = *(const bh8*)(kp);                                                  \
    kf[1] = *(const bh8*)(kp + 32);                                             \
    kf[2] = *(const bh8*)(kp + 16 * ND);                                        \
    kf[3] = *(const bh8*)(kp + 16 * ND + 32);                                   \
    _Pragma("unroll")                                                           \
    for (int r = 0; r < 4; ++r)                                                 \
      mw[r] = mbits[(long)(mbase + r0q + r) * NW32 + (kk0 >> 5)];               \
  } while (0)

#define COMPUTEG(kf, mw, g) do {                                                \
    _Pragma("unroll")                                                           \
    for (int h = 0; h < 2; ++h) {                                               \
      f32x4 acc = {0.f, 0.f, 0.f, 0.f};                                         \
      acc = __builtin_amdgcn_mfma_f32_16x16x32_bf16(aq[0], kf[2*h],   acc,0,0,0);\
      acc = __builtin_amdgcn_mfma_f32_16x16x32_bf16(aq[1], kf[2*h+1], acc,0,0,0);\
      const int key = col0 + (g) * 32 + h * 16 + n16;                           \
      _Pragma("unroll")                                                         \
      for (int r = 0; r < 4; ++r) {                                             \
        const unsigned bit = (mw[r] >> (h * 16 + n16)) & 1u;                    \
        const float e = bit ? __expf(acc[r]) : 0.f;                             \
        rsum[r] += e;                                                           \
        ebuf[(r0q + r) * EB_STRIDE + key] = f2bf(e);                            \
      }                                                                         \
    }                                                                           \
  } while (0)

  {
    bh8 kfA[4], kfB[4];
    unsigned mwA[4], mwB[4];
    LOADG(kfA, mwA, 0); LOADG(kfB, mwB, 1);
    COMPUTEG(kfA, mwA, 0); LOADG(kfA, mwA, 2);
    COMPUTEG(kfB, mwB, 1); LOADG(kfB, mwB, 3);
    COMPUTEG(kfA, mwA, 2); LOADG(kfA, mwA, 4);
    COMPUTEG(kfB, mwB, 3); LOADG(kfB, mwB, 5);
    COMPUTEG(kfA, mwA, 4); LOADG(kfA, mwA, 6);
    COMPUTEG(kfB, mwB, 5); LOADG(kfB, mwB, 7);
    COMPUTEG(kfA, mwA, 6);
    COMPUTEG(kfB, mwB, 7);
  }
#undef LOADG
#undef COMPUTEG

  // ---- Phase 3 setup + V prefetch (global loads, no LDS dependency -> issue NOW so
  // the data crosses the softmax barriers in flight).
  const int dtile = wave & 3;
  const int khalf = wave >> 2;
  const int kb    = khalf * 1024;
  const unsigned short* vrow = vt + ((long)(b * 64 + dtile * 16 + n16)) * NS + kb + quad * 8;
  bh8 vA[2], vB[2], vC[2];
  vA[0] = *(const bh8*)(vrow);        vA[1] = *(const bh8*)(vrow + 32);
  vB[0] = *(const bh8*)(vrow + 64);   vB[1] = *(const bh8*)(vrow + 96);
  vC[0] = *(const bh8*)(vrow + 128);  vC[1] = *(const bh8*)(vrow + 160);

  #pragma unroll
  for (int r = 0; r < 4; ++r) {
    float s = rsum[r];
    s += __shfl_xor(s, 1);
    s += __shfl_xor(s, 2);
    s += __shfl_xor(s, 4);
    s += __shfl_xor(s, 8);
    if (n16 == 0) rowsumP[(r0q + r) * 8 + wave] = s;
  }
  __syncthreads();
  if (tid < 16) {
    float l = 0.f;
    #pragma unroll
    for (int c = 0; c < 8; ++c) l += rowsumP[tid * 8 + c];
    invl[tid] = 1.f / l;
  }
  __syncthreads();

  // ---- Phase 2+3 merged: O = P V via MFMA, one attn row-store per pair of MFMAs.
  // Depth-3 register pipeline: 3 rotating buffer sets, prefetch distance 2 steps.
  float* aout = outA + ((long)(b * NS + mbase)) * NS;
  const int c4 = tid * 4;
  f32x4 il4[4];                        // attn path only (all indices compile-time)
  il4[0] = *(const f32x4*)(invl);
  il4[1] = *(const f32x4*)(invl + 4);
  il4[2] = *(const f32x4*)(invl + 8);
  il4[3] = *(const f32x4*)(invl + 12);

  const unsigned short* ebp = ebuf + n16 * EB_STRIDE + kb + quad * 8;
  bh8 aA[2], aB[2], aC[2];
  aA[0] = *(const bh8*)(ebp);        aA[1] = *(const bh8*)(ebp + 32);
  aB[0] = *(const bh8*)(ebp + 64);   aB[1] = *(const bh8*)(ebp + 96);
  aC[0] = *(const bh8*)(ebp + 128);  aC[1] = *(const bh8*)(ebp + 160);

  f32x4 oacc = {0.f, 0.f, 0.f, 0.f};

#define PVSTEP(p, aa, vv) do {                                                  \
    oacc = __builtin_amdgcn_mfma_f32_16x16x32_bf16(aa[0], vv[0], oacc, 0,0,0);  \
    oacc = __builtin_amdgcn_mfma_f32_16x16x32_bf16(aa[1], vv[1], oacc, 0,0,0);  \
    if ((p) <= 12) {                                                            \
      vv[0] = *(const bh8*)(vrow + ((p)+3) * 64);                               \
      vv[1] = *(const bh8*)(vrow + ((p)+3) * 64 + 32);                          \
      aa[0] = *(const bh8*)(ebp  + ((p)+3) * 64);                               \
      aa[1] = *(const bh8*)(ebp  + ((p)+3) * 64 + 32);                          \
    }                                                                           \
    {                                                                           \
      const float il = il4[(p) >> 2][(p) & 3];                                  \
      uint2 raw = *(const uint2*)(ebuf + (p) * EB_STRIDE + c4);                 \
      f32x4 o;                                                                  \
      o[0] = bf2f(raw.x & 0xffffu) * il;                                        \
      o[1] = bf2f(raw.x >> 16)     * il;                                        \
      o[2] = bf2f(raw.y & 0xffffu) * il;                                        \
      o[3] = bf2f(raw.y >> 16)     * il;                                        \
      __builtin_nontemporal_store(o, (f32x4*)(aout + (long)(p) * NS + c4));     \
    }                                                                           \
  } while (0)

  PVSTEP(0,  aA, vA); PVSTEP(1,  aB, vB); PVSTEP(2,  aC, vC);
  PVSTEP(3,  aA, vA); PVSTEP(4,  aB, vB); PVSTEP(5,  aC, vC);
  PVSTEP(6,  aA, vA); PVSTEP(7,  aB, vB); PVSTEP(8,  aC, vC);
  PVSTEP(9,  aA, vA); PVSTEP(10, aB, vB); PVSTEP(11, aC, vC);
  PVSTEP(12, aA, vA); PVSTEP(13, aB, vB); PVSTEP(14, aC, vC);
  PVSTEP(15, aA, vA);
#undef PVSTEP

  // K-half reduce via LDS, then scale by invl and store O.
  if (khalf == 1) *(f32x4*)(osum + (dtile * 64 + lane) * 4) = oacc;
  __syncthreads();
  if (khalf == 0) {
    f32x4 other = *(const f32x4*)(osum + (dtile * 64 + lane) * 4);
    #pragma unroll
    for (int r = 0; r < 4; ++r) {
      const int lrow = quad * 4 + r;   // C/D: col = n16 (d), row = quad*4+r (query row)
      __builtin_nontemporal_store(
          (oacc[r] + other[r]) * invl[lrow],
          outO + ((long)(b * NS + mbase + lrow)) * ND + dtile * 16 + n16);
    }
  }
}

extern "C" void kernel_launch(void* const* d_in, const int* in_sizes, int n_in,
                              void* d_out, int out_size, void* d_ws, size_t ws_size,
                              hipStream_t stream) {
  const float* q    = (const float*)d_in[0];
  const float* k    = (const float*)d_in[1];
  const float* v    = (const float*)d_in[2];
  const int*   mask = (const int*)d_in[3];
  float* outO = (float*)d_out;                      // [16,2048,64]
  float* outA = outO + (long)NB * NS * ND;          // [16,2048,2048]

  // workspace: vt [16][64][2048] bf16 | kbf [16][2048][64] bf16 | mbits [2048][64] u32
  unsigned short* vt    = (unsigned short*)d_ws;
  unsigned short* kbf   = vt + (long)NB * ND * NS;
  unsigned*       mbits = (unsigned*)(kbf + (long)NB * NS * ND);

  prep_kv_kernel<<<dim3(NS / 64, NB), 256, 0, stream>>>(v, k, vt, kbf);
  maskpack_kernel<<<dim3(NS / 256, NS), 256, 0, stream>>>(mask, mbits);

  const size_t lds = (size_t)(MTILE * EB_STRIDE) * sizeof(short)
                   + (size_t)(16 * 8 + 16 + 4 * 64 * 4) * sizeof(float);
  hipFuncSetAttribute((const void*)sdpa_fused_kernel,
                      hipFuncAttributeMaxDynamicSharedMemorySize, (int)lds);
  sdpa_fused_kernel<<<dim3(NS / MTILE, NB), 512, lds, stream>>>(q, kbf, mbits, vt, outO, outA);
}